// Round 13
// baseline (1021.049 us; speedup 1.0000x reference)
//
#include <hip/hip_runtime.h>
#include <hip/hip_fp16.h>

#define NN 100000
#define NE 1600000
#define NF 64
#define DM 32
#define NG 64
#define NC 10
#define BN_EPS 1e-5f

#define BSHIFT 8
#define NBUCK ((NN + 255) >> 8)        // 391 buckets of 256 nodes
#define CHUNK 8192                     // edges per binning block
#define NCH ((NE + CHUNK - 1) / CHUNK) // 196

// ---- fp16 pack/unpack helpers (RNE) ----
__device__ __forceinline__ float2 up2(unsigned u) {
    __half2 h = __builtin_bit_cast(__half2, u);
    return __half22float2(h);
}
__device__ __forceinline__ unsigned pk2(float a, float b) {
    __half2 h = __floats2half2_rn(a, b);
    return __builtin_bit_cast(unsigned, h);
}
__device__ __forceinline__ void acc8(float* a, uint4 w) {
    float2 p;
    p = up2(w.x); a[0] += p.x; a[1] += p.y;
    p = up2(w.y); a[2] += p.x; a[3] += p.y;
    p = up2(w.z); a[4] += p.x; a[5] += p.y;
    p = up2(w.w); a[6] += p.x; a[7] += p.y;
}

// ============ CSR build via bucket counting-sort ============
__global__ __launch_bounds__(256) void binA_k(const int* __restrict__ ei,
                                              int* __restrict__ bcnt) {
    __shared__ int h[NBUCK];
    for (int i = threadIdx.x; i < NBUCK; i += 256) h[i] = 0;
    __syncthreads();
    long long base = (long long)blockIdx.x * CHUNK;
    int n = (int)((NE - base < CHUNK) ? (NE - base) : CHUNK);
    for (int i = threadIdx.x; i < n; i += 256) {
        int d = ei[NE + base + i];
        atomicAdd(&h[d >> BSHIFT], 1);
    }
    __syncthreads();
    for (int i = threadIdx.x; i < NBUCK; i += 256)
        if (h[i]) atomicAdd(&bcnt[i], h[i]);
}

__global__ __launch_bounds__(512) void binB_k(const int* __restrict__ bcnt,
                                              int* __restrict__ bbase,
                                              int* __restrict__ bcur) {
    __shared__ int s[512];
    int t = threadIdx.x;
    int v = (t < NBUCK) ? bcnt[t] : 0;
    s[t] = v;
    __syncthreads();
    int acc = v;
    for (int off = 1; off < 512; off <<= 1) {
        int add = (t >= off) ? s[t - off] : 0;
        __syncthreads();
        acc += add;
        s[t] = acc;
        __syncthreads();
    }
    if (t < NBUCK) { bbase[t] = acc - v; bcur[t] = acc - v; }
    if (t == 0) bbase[NBUCK] = NE;
}

__global__ __launch_bounds__(256) void binC_k(const int* __restrict__ ei,
                                              int* __restrict__ bcur,
                                              unsigned* __restrict__ binned) {
    __shared__ int cnt[NBUCK];
    __shared__ int ofs[NBUCK];
    __shared__ int idx[NBUCK];
    for (int i = threadIdx.x; i < NBUCK; i += 256) { cnt[i] = 0; idx[i] = 0; }
    __syncthreads();
    long long base = (long long)blockIdx.x * CHUNK;
    int n = (int)((NE - base < CHUNK) ? (NE - base) : CHUNK);
    int d[CHUNK / 256];
#pragma unroll
    for (int k = 0; k < CHUNK / 256; k++) {
        int i = threadIdx.x + k * 256;
        int dd = (i < n) ? ei[NE + base + i] : -1;
        d[k] = dd;
        if (dd >= 0) atomicAdd(&cnt[dd >> BSHIFT], 1);
    }
    __syncthreads();
    for (int i = threadIdx.x; i < NBUCK; i += 256)
        if (cnt[i]) ofs[i] = atomicAdd(&bcur[i], cnt[i]);
    __syncthreads();
#pragma unroll
    for (int k = 0; k < CHUNK / 256; k++) {
        int i = threadIdx.x + k * 256;
        if (i < n) {
            unsigned src = (unsigned)ei[base + i];
            int b = d[k] >> BSHIFT;
            int l = atomicAdd(&idx[b], 1);
            binned[ofs[b] + l] = (src << 8) | (unsigned)(d[k] & 255);
        }
    }
}

__global__ __launch_bounds__(256) void binD_k(const unsigned* __restrict__ binned,
                                              const int* __restrict__ bbase,
                                              int* __restrict__ rowptr,
                                              int* __restrict__ csr) {
    __shared__ int cnt[256];
    __shared__ int cur[256];
    __shared__ int s[256];
    int b = blockIdx.x;
    int e0 = bbase[b], e1 = bbase[b + 1];
    int t = threadIdx.x;
    cnt[t] = 0;
    __syncthreads();
    for (int e = e0 + t; e < e1; e += 256) atomicAdd(&cnt[binned[e] & 255u], 1);
    __syncthreads();
    int v = cnt[t];
    s[t] = v;
    __syncthreads();
    int acc = v;
    for (int off = 1; off < 256; off <<= 1) {
        int add = (t >= off) ? s[t - off] : 0;
        __syncthreads();
        acc += add;
        s[t] = acc;
        __syncthreads();
    }
    int base = e0 + acc - v;
    int node = (b << BSHIFT) + t;
    if (node < NN) rowptr[node] = base;
    cur[t] = base;
    if (b == NBUCK - 1 && t == 0) rowptr[NN] = NE;
    __syncthreads();
    for (int e = e0 + t; e < e1; e += 256) {
        unsigned w = binned[e];
        int p = atomicAdd(&cur[w & 255u], 1);
        csr[p] = (int)(w >> 8);
    }
}

// ============ pre-pass layer 1: yhf = fp16(x @ W1a), 4 lanes/node; zero accumulators ============
__global__ __launch_bounds__(256) void pre1_k(const float* __restrict__ x,
                                              const float* __restrict__ wa,
                                              unsigned* __restrict__ yhf,
                                              float* __restrict__ zbuf) {
    __shared__ float sWa[64 * 32];
    int tid = threadIdx.x;
    if (blockIdx.x == 0) {
        for (int i = tid; i < 5 * 64 + NG * 32; i += 256) zbuf[i] = 0.f;
    }
    for (int i = tid; i < 64 * 32; i += 256) sWa[i] = wa[i];
    __syncthreads();
    int l = tid & 3;
    int node = blockIdx.x * 64 + (tid >> 2);
    if (node >= NN) return;
    float t[8];
#pragma unroll
    for (int j = 0; j < 8; j++) t[j] = 0.f;
    const float4* xr = reinterpret_cast<const float4*>(x + (long long)node * 64);
    const float4* w4 = reinterpret_cast<const float4*>(sWa);
#pragma unroll
    for (int k4 = 0; k4 < 16; k4++) {
        float4 xv = xr[k4];
        float av[4] = {xv.x, xv.y, xv.z, xv.w};
#pragma unroll
        for (int i = 0; i < 4; i++) {
            float a = av[i];
            float4 w0 = w4[(k4 * 4 + i) * 8 + 2 * l];
            float4 w1 = w4[(k4 * 4 + i) * 8 + 2 * l + 1];
            t[0] += a * w0.x; t[1] += a * w0.y; t[2] += a * w0.z; t[3] += a * w0.w;
            t[4] += a * w1.x; t[5] += a * w1.y; t[6] += a * w1.z; t[7] += a * w1.w;
        }
    }
    uint4 p;
    p.x = pk2(t[0], t[1]); p.y = pk2(t[2], t[3]);
    p.z = pk2(t[4], t[5]); p.w = pk2(t[6], t[7]);
    reinterpret_cast<uint4*>(yhf)[(long long)node * 4 + l] = p;
}

// ============ fused gather + MLP + BN-stats ============
// 16 lanes/node (4 feat-lanes x 4 edge-groups), 16 nodes/block (grid 6250).
// Gather: lane (eg,fl) walks edges [s+eg*chunk, ...) loading uint4 t4[src*4+fl]
//   -> per wave-instruction 16 distinct rows (R10 coalescing), per-lane chain len/4.
// Reduce across eg via shfl_down(8),(4); eg0 lanes stage gsum; MLP with 16 lanes
// x 2 feats (float2 weights, stride-17 stage).
#define SST 17
template <int MODE>
__global__ __launch_bounds__(256) void fused_k(const unsigned* __restrict__ tblIn,
                                               unsigned* __restrict__ tblOut,
                                               const int* __restrict__ rowptr,
                                               const int* __restrict__ csr,
                                               const float* __restrict__ wa,
                                               const float* __restrict__ ba,
                                               const float* __restrict__ wb,
                                               const float* __restrict__ bb,
                                               const float* __restrict__ stPrev,
                                               const float* __restrict__ gammaPrev,
                                               const float* __restrict__ betaPrev,
                                               float* __restrict__ statsOut) {
    __shared__ float sWa[32 * 32];
    __shared__ float sWb[32 * 32];
    __shared__ float sBa[32], sBb[32];
    __shared__ float sSc[32], sSh[32];
    __shared__ float sStage[32 * SST];
    __shared__ float sSum[4 * 32], sSq[4 * 32];
    int tid = threadIdx.x;
    for (int i = tid; i < 32 * 32; i += 256) {
        sWb[i] = wb[i];
        if (MODE) sWa[i] = wa[i];
    }
    if (tid < 32) {
        sBa[tid] = ba[tid];
        sBb[tid] = bb[tid];
        if (MODE) {
            const float invn = 1.0f / NN;
            float mu = stPrev[tid] * invn;
            float var = stPrev[32 + tid] * invn - mu * mu;
            float scale = rsqrtf(var + BN_EPS) * gammaPrev[tid];
            sSc[tid] = scale;
            sSh[tid] = betaPrev[tid] - mu * scale;
        }
    }

    int fl = tid & 3;                 // feature slice: feats fl*8..fl*8+7 (uint4)
    int eg = (tid >> 2) & 3;          // edge group
    int nl = tid >> 4;                // node in block (0..15)
    int node = blockIdx.x * 16 + nl;  // NN = 6250*16 exactly

    int s = rowptr[node], e = rowptr[node + 1];
    int len = e - s;
    int chunk = (len + 3) >> 2;
    int i0 = s + eg * chunk;
    int i1 = i0 + chunk;
    if (i1 > e) i1 = e;
    if (i0 > e) i0 = e;

    const uint4* t4 = reinterpret_cast<const uint4*>(tblIn);
    float g[8];
#pragma unroll
    for (int c = 0; c < 8; c++) g[c] = 0.f;
    int i = i0;
    for (; i + 4 <= i1; i += 4) {
        int s0 = csr[i], s1 = csr[i + 1], s2 = csr[i + 2], s3 = csr[i + 3];
        uint4 w0 = t4[(long long)s0 * 4 + fl];
        uint4 w1 = t4[(long long)s1 * 4 + fl];
        uint4 w2 = t4[(long long)s2 * 4 + fl];
        uint4 w3 = t4[(long long)s3 * 4 + fl];
        acc8(g, w0); acc8(g, w1); acc8(g, w2); acc8(g, w3);
    }
    for (; i < i1; i++) {
        uint4 w = t4[(long long)csr[i] * 4 + fl];
        acc8(g, w);
    }

    // ---- reduce across edge-groups (lanes +4, +8 within 16-lane node group) ----
#pragma unroll
    for (int c = 0; c < 8; c++) {
        float v = g[c];
        v += __shfl_down(v, 8, 64);
        v += __shfl_down(v, 4, 64);
        g[c] = v;
    }
    __syncthreads();   // weights/biases/BN staged; stage free
    if (eg == 0) {
#pragma unroll
        for (int c = 0; c < 8; c++) sStage[(fl * 8 + c) * SST + nl] = g[c];
    }
    __syncthreads();

    // ---- MLP: 16 lanes/node, 2 feats each ----
    int l = tid & 15;
    int f0 = 2 * l, f1 = 2 * l + 1;
    float2 sp = up2(tblIn[(long long)node * 16 + l]);
    float g0 = sStage[f0 * SST + nl];
    float g1 = sStage[f1 * SST + nl];
    float t0, t1;
    if (MODE) {
        float deg = (float)len;
        // same lane reads then overwrites its own slots -> no sync needed between
        float in0 = sp.x * sSc[f0] + sSh[f0] + g0 * sSc[f0] + deg * sSh[f0];
        float in1 = sp.y * sSc[f1] + sSh[f1] + g1 * sSc[f1] + deg * sSh[f1];
        sStage[f0 * SST + nl] = in0;
        sStage[f1 * SST + nl] = in1;
        __syncthreads();
        t0 = sBa[f0]; t1 = sBa[f1];
        const float2* w2a = reinterpret_cast<const float2*>(sWa);
#pragma unroll
        for (int k = 0; k < 32; k++) {
            float a = sStage[k * SST + nl];
            float2 w = w2a[k * 16 + l];
            t0 += a * w.x;
            t1 += a * w.y;
        }
        t0 = fmaxf(t0, 0.f);
        t1 = fmaxf(t1, 0.f);
        __syncthreads();   // all GEMM1 reads done before stage reuse
    } else {
        t0 = fmaxf(sp.x + g0 + sBa[f0], 0.f);
        t1 = fmaxf(sp.y + g1 + sBa[f1], 0.f);
        __syncthreads();   // gsum reads done before stage reuse
    }

    sStage[f0 * SST + nl] = t0;
    sStage[f1 * SST + nl] = t1;
    __syncthreads();
    float r0 = sBb[f0], r1 = sBb[f1];
    const float2* w2b = reinterpret_cast<const float2*>(sWb);
#pragma unroll
    for (int k = 0; k < 32; k++) {
        float a = sStage[k * SST + nl];
        float2 w = w2b[k * 16 + l];
        r0 += a * w.x;
        r1 += a * w.y;
    }
    r0 = fmaxf(r0, 0.f);
    r1 = fmaxf(r1, 0.f);

    // only one lane per (node, feat-pair) writes: lanes 0..15 of each node group
    if (eg == (l >> 2) ? true : true) { /* all 16 lanes unique l -> all write */ }
    tblOut[(long long)node * 16 + l] = pk2(r0, r1);

    // ---- stats: each lane owns feats {2l,2l+1}; reduce the wave's 4 nodes ----
    int lane = tid & 63, wid = tid >> 6;
    float v0 = r0, q0 = r0 * r0, v1 = r1, q1 = r1 * r1;
    v0 += __shfl_down(v0, 32, 64); q0 += __shfl_down(q0, 32, 64);
    v1 += __shfl_down(v1, 32, 64); q1 += __shfl_down(q1, 32, 64);
    v0 += __shfl_down(v0, 16, 64); q0 += __shfl_down(q0, 16, 64);
    v1 += __shfl_down(v1, 16, 64); q1 += __shfl_down(q1, 16, 64);
    if (lane < 16) {
        sSum[wid * 32 + 2 * lane] = v0;
        sSum[wid * 32 + 2 * lane + 1] = v1;
        sSq[wid * 32 + 2 * lane] = q0;
        sSq[wid * 32 + 2 * lane + 1] = q1;
    }
    __syncthreads();
    if (tid < 32) {
        float a = sSum[tid] + sSum[32 + tid] + sSum[64 + tid] + sSum[96 + tid];
        float b = sSq[tid] + sSq[32 + tid] + sSq[64 + tid] + sSq[96 + tid];
        atomicAdd(&statsOut[tid], a);
        atomicAdd(&statsOut[32 + tid], b);
    }
}

// ============ pool (fp16 table) with fused BN of layer 5, privatized atomics ============
#define POOL_NPB 512
__global__ __launch_bounds__(256) void pool_bn_k(const unsigned* __restrict__ tbl,
                                                 const int* __restrict__ batch,
                                                 const float* __restrict__ st,
                                                 const float* __restrict__ gamma,
                                                 const float* __restrict__ beta,
                                                 float* __restrict__ pooled) {
    int tid = threadIdx.x;
    int f = tid & 31;
    int p = tid >> 5;
    int wrd = f >> 1;
    int hi = f & 1;
    int n0 = blockIdx.x * POOL_NPB + p * (POOL_NPB / 8);
    int n1 = n0 + POOL_NPB / 8;
    if (n1 > NN) n1 = NN;
    if (n0 >= NN) return;
    const float invn = 1.0f / NN;
    float mu = st[f] * invn;
    float var = st[32 + f] * invn - mu * mu;
    float sc = rsqrtf(var + BN_EPS) * gamma[f];
    float sh = beta[f] - mu * sc;
    float acc = 0.f;
    int cur = batch[n0];
    for (int n = n0; n < n1; n++) {
        int g = batch[n];
        if (g != cur) {
            atomicAdd(&pooled[cur * 32 + f], acc);
            cur = g;
            acc = 0.f;
        }
        float2 pv = up2(tbl[(long long)n * 16 + wrd]);
        acc += (hi ? pv.y : pv.x) * sc + sh;
    }
    atomicAdd(&pooled[cur * 32 + f], acc);
}

// ============ final FCs ============
__global__ __launch_bounds__(64) void final_k(const float* __restrict__ pooled,
                                              const float* __restrict__ w1,
                                              const float* __restrict__ b1,
                                              const float* __restrict__ w2,
                                              const float* __restrict__ b2,
                                              float* __restrict__ out) {
    int g = threadIdx.x;
    if (g >= NG) return;
    float t[32];
#pragma unroll
    for (int j = 0; j < 32; j++) t[j] = b1[j];
    for (int k = 0; k < 32; k++) {
        float a = pooled[g * 32 + k];
#pragma unroll
        for (int j = 0; j < 32; j++) t[j] += a * w1[k * 32 + j];
    }
#pragma unroll
    for (int j = 0; j < 32; j++) t[j] = fmaxf(t[j], 0.f);
    for (int c = 0; c < NC; c++) {
        float o = b2[c];
#pragma unroll
        for (int k = 0; k < 32; k++) o += t[k] * w2[k * NC + c];
        out[g * NC + c] = o;
    }
}

extern "C" void kernel_launch(void* const* d_in, const int* in_sizes, int n_in,
                              void* d_out, int out_size, void* d_ws, size_t ws_size,
                              hipStream_t stream) {
    const float* x = (const float*)d_in[0];
    const int* ei = (const int*)d_in[1];
    const int* batch = (const int*)d_in[2];
    const float* w1a = (const float*)d_in[3];
    const float* b1a = (const float*)d_in[4];
    const float* w1b = (const float*)d_in[5];
    const float* b1b = (const float*)d_in[6];
    const float* Wa = (const float*)d_in[7];
    const float* Ba = (const float*)d_in[8];
    const float* Wb = (const float*)d_in[9];
    const float* Bb = (const float*)d_in[10];
    const float* bn_gamma = (const float*)d_in[11];
    const float* bn_beta = (const float*)d_in[12];
    const float* fc1w = (const float*)d_in[13];
    const float* fc1b = (const float*)d_in[14];
    const float* fc2w = (const float*)d_in[15];
    const float* fc2b = (const float*)d_in[16];
    float* out = (float*)d_out;

    float* ws = (float*)d_ws;
    float* stats_all = ws;                            // 5*64
    float* pooled = stats_all + 5 * 64;               // NG*32
    unsigned* yhf = (unsigned*)(pooled + NG * 32);    // NN*16 uints (32 fp16/row)
    unsigned* hfA = yhf + (size_t)NN * 16;            // NN*16
    unsigned* hfB = hfA + (size_t)NN * 16;            // NN*16
    unsigned* binned = hfB + (size_t)NN * 16;         // NE
    int* bcnt = (int*)(binned + NE);                  // NBUCK
    int* bbase = bcnt + NBUCK;                        // NBUCK+1
    int* bcur = bbase + NBUCK + 1;                    // NBUCK
    int* rowptr = bcur + NBUCK;                       // NN+1
    int* csr = rowptr + NN + 1;                       // NE

    const int nbPre = (NN + 63) / 64;   // pre1: 4 lanes/node
    const int nbF = NN / 16;            // fused: 16 lanes/node, 6250 blocks

    // ---- CSR build (bucketed, packed) ----
    hipMemsetAsync(bcnt, 0, NBUCK * sizeof(int), stream);
    binA_k<<<NCH, 256, 0, stream>>>(ei, bcnt);
    binB_k<<<1, 512, 0, stream>>>(bcnt, bbase, bcur);
    binC_k<<<NCH, 256, 0, stream>>>(ei, bcur, binned);
    binD_k<<<NBUCK, 256, 0, stream>>>(binned, bbase, rowptr, csr);

    // ---- layer 1: yhf = fp16(x@W1a) (+zero stats/pooled); fused gather+tail ----
    pre1_k<<<nbPre, 256, 0, stream>>>(x, w1a, yhf, stats_all);
    fused_k<0><<<nbF, 256, 0, stream>>>(yhf, hfA, rowptr, csr,
                                        nullptr, b1a, w1b, b1b,
                                        nullptr, nullptr, nullptr, stats_all);

    // ---- layers 2-5: fused gather(BN-prev) + MLP; fp16 table ping-pong ----
    unsigned* tin = hfA;
    unsigned* tout = hfB;
    for (int i = 0; i < 4; i++) {
        fused_k<1><<<nbF, 256, 0, stream>>>(tin, tout, rowptr, csr,
                                            Wa + i * 1024, Ba + i * 32,
                                            Wb + i * 1024, Bb + i * 32,
                                            stats_all + i * 64, bn_gamma + i * 32,
                                            bn_beta + i * 32, stats_all + (i + 1) * 64);
        unsigned* tmp = tin; tin = tout; tout = tmp;
    }

    // ---- pool (BN5 fused, fp16 table) + FCs ----
    pool_bn_k<<<(NN + POOL_NPB - 1) / POOL_NPB, 256, 0, stream>>>(
        tin, batch, stats_all + 4 * 64, bn_gamma + 4 * 32, bn_beta + 4 * 32, pooled);
    final_k<<<1, 64, 0, stream>>>(pooled, fc1w, fc1b, fc2w, fc2b, out);
}

// Round 14
// 576.610 us; speedup vs baseline: 1.7708x; 1.7708x over previous
//
#include <hip/hip_runtime.h>
#include <hip/hip_fp16.h>

#define NN 100000
#define NE 1600000
#define NF 64
#define DM 32
#define NG 64
#define NC 10
#define BN_EPS 1e-5f
#define NTILE0 50000                   // src-tile boundary: tile0 table slice = 3.2MB < 4MB L2

#define BSHIFT 8
#define NBUCK ((NN + 255) >> 8)        // 391 buckets of 256 nodes
#define CHUNK 8192                     // edges per binning block
#define NCH ((NE + CHUNK - 1) / CHUNK) // 196

// ---- fp16 pack/unpack helpers (RNE) ----
__device__ __forceinline__ float2 up2(unsigned u) {
    __half2 h = __builtin_bit_cast(__half2, u);
    return __half22float2(h);
}
__device__ __forceinline__ unsigned pk2(float a, float b) {
    __half2 h = __floats2half2_rn(a, b);
    return __builtin_bit_cast(unsigned, h);
}
__device__ __forceinline__ void acc8(float* a, uint4 w) {
    float2 p;
    p = up2(w.x); a[0] += p.x; a[1] += p.y;
    p = up2(w.y); a[2] += p.x; a[3] += p.y;
    p = up2(w.z); a[4] += p.x; a[5] += p.y;
    p = up2(w.w); a[6] += p.x; a[7] += p.y;
}

// ============ CSR build via bucket counting-sort ============
__global__ __launch_bounds__(256) void binA_k(const int* __restrict__ ei,
                                              int* __restrict__ bcnt) {
    __shared__ int h[NBUCK];
    for (int i = threadIdx.x; i < NBUCK; i += 256) h[i] = 0;
    __syncthreads();
    long long base = (long long)blockIdx.x * CHUNK;
    int n = (int)((NE - base < CHUNK) ? (NE - base) : CHUNK);
    for (int i = threadIdx.x; i < n; i += 256) {
        int d = ei[NE + base + i];
        atomicAdd(&h[d >> BSHIFT], 1);
    }
    __syncthreads();
    for (int i = threadIdx.x; i < NBUCK; i += 256)
        if (h[i]) atomicAdd(&bcnt[i], h[i]);
}

__global__ __launch_bounds__(512) void binB_k(const int* __restrict__ bcnt,
                                              int* __restrict__ bbase,
                                              int* __restrict__ bcur) {
    __shared__ int s[512];
    int t = threadIdx.x;
    int v = (t < NBUCK) ? bcnt[t] : 0;
    s[t] = v;
    __syncthreads();
    int acc = v;
    for (int off = 1; off < 512; off <<= 1) {
        int add = (t >= off) ? s[t - off] : 0;
        __syncthreads();
        acc += add;
        s[t] = acc;
        __syncthreads();
    }
    if (t < NBUCK) { bbase[t] = acc - v; bcur[t] = acc - v; }
    if (t == 0) bbase[NBUCK] = NE;
}

__global__ __launch_bounds__(256) void binC_k(const int* __restrict__ ei,
                                              int* __restrict__ bcur,
                                              unsigned* __restrict__ binned) {
    __shared__ int cnt[NBUCK];
    __shared__ int ofs[NBUCK];
    __shared__ int idx[NBUCK];
    for (int i = threadIdx.x; i < NBUCK; i += 256) { cnt[i] = 0; idx[i] = 0; }
    __syncthreads();
    long long base = (long long)blockIdx.x * CHUNK;
    int n = (int)((NE - base < CHUNK) ? (NE - base) : CHUNK);
    int d[CHUNK / 256];
#pragma unroll
    for (int k = 0; k < CHUNK / 256; k++) {
        int i = threadIdx.x + k * 256;
        int dd = (i < n) ? ei[NE + base + i] : -1;
        d[k] = dd;
        if (dd >= 0) atomicAdd(&cnt[dd >> BSHIFT], 1);
    }
    __syncthreads();
    for (int i = threadIdx.x; i < NBUCK; i += 256)
        if (cnt[i]) ofs[i] = atomicAdd(&bcur[i], cnt[i]);
    __syncthreads();
#pragma unroll
    for (int k = 0; k < CHUNK / 256; k++) {
        int i = threadIdx.x + k * 256;
        if (i < n) {
            unsigned src = (unsigned)ei[base + i];
            int b = d[k] >> BSHIFT;
            int l = atomicAdd(&idx[b], 1);
            binned[ofs[b] + l] = (src << 8) | (unsigned)(d[k] & 255);
        }
    }
}

// D: per-node lists with tile-0 srcs first; emits rowptr + split
__global__ __launch_bounds__(256) void binD_k(const unsigned* __restrict__ binned,
                                              const int* __restrict__ bbase,
                                              int* __restrict__ rowptr,
                                              int* __restrict__ splitp,
                                              int* __restrict__ csr) {
    __shared__ int cntLo[256], cntHi[256];
    __shared__ int curLo[256], curHi[256];
    __shared__ int s[256];
    int b = blockIdx.x;
    int e0 = bbase[b], e1 = bbase[b + 1];
    int t = threadIdx.x;
    cntLo[t] = 0; cntHi[t] = 0;
    __syncthreads();
    for (int e = e0 + t; e < e1; e += 256) {
        unsigned w = binned[e];
        int ld = (int)(w & 255u);
        int src = (int)(w >> 8);
        atomicAdd(src < NTILE0 ? &cntLo[ld] : &cntHi[ld], 1);
    }
    __syncthreads();
    int v = cntLo[t] + cntHi[t];
    s[t] = v;
    __syncthreads();
    int acc = v;
    for (int off = 1; off < 256; off <<= 1) {
        int add = (t >= off) ? s[t - off] : 0;
        __syncthreads();
        acc += add;
        s[t] = acc;
        __syncthreads();
    }
    int base = e0 + acc - v;
    int node = (b << BSHIFT) + t;
    if (node < NN) {
        rowptr[node] = base;
        splitp[node] = base + cntLo[t];
    }
    curLo[t] = base;
    curHi[t] = base + cntLo[t];
    if (b == NBUCK - 1 && t == 0) rowptr[NN] = NE;
    __syncthreads();
    for (int e = e0 + t; e < e1; e += 256) {
        unsigned w = binned[e];
        int ld = (int)(w & 255u);
        int src = (int)(w >> 8);
        int p = atomicAdd(src < NTILE0 ? &curLo[ld] : &curHi[ld], 1);
        csr[p] = src;
    }
}

// ============ pre-pass layer 1: yhf = fp16(x @ W1a), 4 lanes/node; zero accumulators ============
__global__ __launch_bounds__(256) void pre1_k(const float* __restrict__ x,
                                              const float* __restrict__ wa,
                                              unsigned* __restrict__ yhf,
                                              float* __restrict__ zbuf) {
    __shared__ float sWa[64 * 32];
    int tid = threadIdx.x;
    if (blockIdx.x == 0) {
        for (int i = tid; i < 5 * 64 + NG * 32; i += 256) zbuf[i] = 0.f;
    }
    for (int i = tid; i < 64 * 32; i += 256) sWa[i] = wa[i];
    __syncthreads();
    int l = tid & 3;
    int node = blockIdx.x * 64 + (tid >> 2);
    if (node >= NN) return;
    float t[8];
#pragma unroll
    for (int j = 0; j < 8; j++) t[j] = 0.f;
    const float4* xr = reinterpret_cast<const float4*>(x + (long long)node * 64);
    const float4* w4 = reinterpret_cast<const float4*>(sWa);
#pragma unroll
    for (int k4 = 0; k4 < 16; k4++) {
        float4 xv = xr[k4];
        float av[4] = {xv.x, xv.y, xv.z, xv.w};
#pragma unroll
        for (int i = 0; i < 4; i++) {
            float a = av[i];
            float4 w0 = w4[(k4 * 4 + i) * 8 + 2 * l];
            float4 w1 = w4[(k4 * 4 + i) * 8 + 2 * l + 1];
            t[0] += a * w0.x; t[1] += a * w0.y; t[2] += a * w0.z; t[3] += a * w0.w;
            t[4] += a * w1.x; t[5] += a * w1.y; t[6] += a * w1.z; t[7] += a * w1.w;
        }
    }
    uint4 p;
    p.x = pk2(t[0], t[1]); p.y = pk2(t[2], t[3]);
    p.z = pk2(t[4], t[5]); p.w = pk2(t[6], t[7]);
    reinterpret_cast<uint4*>(yhf)[(long long)node * 4 + l] = p;
}

// ============ pass 0: gather tile-0 srcs only (3.2MB working set, L2-resident) ============
// 4 lanes/node, uint4/lane, unroll x8; writes fp32 partial sums to agg.
__global__ __launch_bounds__(256) void gather0_k(const unsigned* __restrict__ tblIn,
                                                 const int* __restrict__ rowptr,
                                                 const int* __restrict__ splitp,
                                                 float* __restrict__ agg) {
    int tid = threadIdx.x;
    int l = tid & 3;
    int node = blockIdx.x * 64 + (tid >> 2);
    if (node >= NN) return;
    int s = rowptr[node], e = splitp[node];
    const uint4* t4 = reinterpret_cast<const uint4*>(tblIn);
    float g[8];
#pragma unroll
    for (int c = 0; c < 8; c++) g[c] = 0.f;
    // (csr index array declared const; loads are sequential, L1-friendly)
    extern const int* __restrict__ csr_dummy_decl;  // no-op
    const int* csr = splitp + NN;  // placeholder overwritten below -- not used
    (void)csr;
    return;  // placeholder removed in real body below
}

// real gather0 (separate name to keep the above from being used)
__global__ __launch_bounds__(256) void gatherT0_k(const unsigned* __restrict__ tblIn,
                                                  const int* __restrict__ rowptr,
                                                  const int* __restrict__ splitp,
                                                  const int* __restrict__ csr,
                                                  float* __restrict__ agg) {
    int tid = threadIdx.x;
    int l = tid & 3;
    int node = blockIdx.x * 64 + (tid >> 2);
    if (node >= NN) return;
    int s = rowptr[node], e = splitp[node];
    const uint4* t4 = reinterpret_cast<const uint4*>(tblIn);
    float g[8];
#pragma unroll
    for (int c = 0; c < 8; c++) g[c] = 0.f;
    int i = s;
    for (; i + 8 <= e; i += 8) {
        int s0 = csr[i], s1 = csr[i + 1], s2 = csr[i + 2], s3 = csr[i + 3];
        int s4 = csr[i + 4], s5 = csr[i + 5], s6 = csr[i + 6], s7 = csr[i + 7];
        uint4 w0 = t4[(long long)s0 * 4 + l];
        uint4 w1 = t4[(long long)s1 * 4 + l];
        uint4 w2 = t4[(long long)s2 * 4 + l];
        uint4 w3 = t4[(long long)s3 * 4 + l];
        uint4 w4 = t4[(long long)s4 * 4 + l];
        uint4 w5 = t4[(long long)s5 * 4 + l];
        uint4 w6 = t4[(long long)s6 * 4 + l];
        uint4 w7 = t4[(long long)s7 * 4 + l];
        acc8(g, w0); acc8(g, w1); acc8(g, w2); acc8(g, w3);
        acc8(g, w4); acc8(g, w5); acc8(g, w6); acc8(g, w7);
    }
    if (i + 4 <= e) {
        int s0 = csr[i], s1 = csr[i + 1], s2 = csr[i + 2], s3 = csr[i + 3];
        uint4 w0 = t4[(long long)s0 * 4 + l];
        uint4 w1 = t4[(long long)s1 * 4 + l];
        uint4 w2 = t4[(long long)s2 * 4 + l];
        uint4 w3 = t4[(long long)s3 * 4 + l];
        acc8(g, w0); acc8(g, w1); acc8(g, w2); acc8(g, w3);
        i += 4;
    }
    for (; i < e; i++) {
        uint4 w = t4[(long long)csr[i] * 4 + l];
        acc8(g, w);
    }
    float4* ar = reinterpret_cast<float4*>(agg + (long long)node * 32 + l * 8);
    float4 o0, o1;
    o0.x = g[0]; o0.y = g[1]; o0.z = g[2]; o0.w = g[3];
    o1.x = g[4]; o1.y = g[5]; o1.z = g[6]; o1.w = g[7];
    ar[0] = o0;
    ar[1] = o1;
}

// ============ pass 1: fused gather (tile-1 srcs) + MLP + BN-stats, R10 structure ============
// g starts from agg (pass-0 partial); gathers [split, rowend); deg = full degree.
#define SSTR 65
template <int MODE>
__global__ __launch_bounds__(256) void fused_k(const unsigned* __restrict__ tblIn,
                                               unsigned* __restrict__ tblOut,
                                               const int* __restrict__ rowptr,
                                               const int* __restrict__ splitp,
                                               const int* __restrict__ csr,
                                               const float* __restrict__ aggIn,
                                               const float* __restrict__ wa,
                                               const float* __restrict__ ba,
                                               const float* __restrict__ wb,
                                               const float* __restrict__ bb,
                                               const float* __restrict__ stPrev,
                                               const float* __restrict__ gammaPrev,
                                               const float* __restrict__ betaPrev,
                                               float* __restrict__ statsOut) {
    __shared__ float sWa[32 * 32];
    __shared__ float sWb[32 * 32];
    __shared__ float sBa[32], sBb[32];
    __shared__ float sSc[32], sSh[32];
    __shared__ float sStage[32 * SSTR];
    __shared__ float sSum[4 * 32], sSq[4 * 32];
    int tid = threadIdx.x;
    for (int i = tid; i < 32 * 32; i += 256) {
        sWb[i] = wb[i];
        if (MODE) sWa[i] = wa[i];
    }
    if (tid < 32) {
        sBa[tid] = ba[tid];
        sBb[tid] = bb[tid];
        if (MODE) {
            const float invn = 1.0f / NN;
            float mu = stPrev[tid] * invn;
            float var = stPrev[32 + tid] * invn - mu * mu;
            float scale = rsqrtf(var + BN_EPS) * gammaPrev[tid];
            sSc[tid] = scale;
            sSh[tid] = betaPrev[tid] - mu * scale;
        }
    }

    int l = tid & 3;
    int nl = tid >> 2;
    int node = blockIdx.x * 64 + nl;
    bool act = node < NN;

    int sf = 0, sp = 0, e = 0;
    uint4 selfw = make_uint4(0, 0, 0, 0);
    float g[8];
#pragma unroll
    for (int c = 0; c < 8; c++) g[c] = 0.f;
    const uint4* t4 = reinterpret_cast<const uint4*>(tblIn);
    if (act) {
        sf = rowptr[node];
        sp = splitp[node];
        e = rowptr[node + 1];
        selfw = t4[(long long)node * 4 + l];
        const float4* ar = reinterpret_cast<const float4*>(aggIn + (long long)node * 32 + l * 8);
        float4 a0 = ar[0], a1 = ar[1];
        g[0] = a0.x; g[1] = a0.y; g[2] = a0.z; g[3] = a0.w;
        g[4] = a1.x; g[5] = a1.y; g[6] = a1.z; g[7] = a1.w;
    }
    int i = sp;
    for (; i + 8 <= e; i += 8) {
        int s0 = csr[i], s1 = csr[i + 1], s2 = csr[i + 2], s3 = csr[i + 3];
        int s4 = csr[i + 4], s5 = csr[i + 5], s6 = csr[i + 6], s7 = csr[i + 7];
        uint4 w0 = t4[(long long)s0 * 4 + l];
        uint4 w1 = t4[(long long)s1 * 4 + l];
        uint4 w2 = t4[(long long)s2 * 4 + l];
        uint4 w3 = t4[(long long)s3 * 4 + l];
        uint4 w4 = t4[(long long)s4 * 4 + l];
        uint4 w5 = t4[(long long)s5 * 4 + l];
        uint4 w6 = t4[(long long)s6 * 4 + l];
        uint4 w7 = t4[(long long)s7 * 4 + l];
        acc8(g, w0); acc8(g, w1); acc8(g, w2); acc8(g, w3);
        acc8(g, w4); acc8(g, w5); acc8(g, w6); acc8(g, w7);
    }
    if (i + 4 <= e) {
        int s0 = csr[i], s1 = csr[i + 1], s2 = csr[i + 2], s3 = csr[i + 3];
        uint4 w0 = t4[(long long)s0 * 4 + l];
        uint4 w1 = t4[(long long)s1 * 4 + l];
        uint4 w2 = t4[(long long)s2 * 4 + l];
        uint4 w3 = t4[(long long)s3 * 4 + l];
        acc8(g, w0); acc8(g, w1); acc8(g, w2); acc8(g, w3);
        i += 4;
    }
    for (; i < e; i++) {
        uint4 w = t4[(long long)csr[i] * 4 + l];
        acc8(g, w);
    }
    __syncthreads();   // weights, biases, BN consts ready; gather done

    // ---- self-row + (BN) combine; stage GEMM input / t ----
    float sv[8];
    {
        float2 p;
        p = up2(selfw.x); sv[0] = p.x; sv[1] = p.y;
        p = up2(selfw.y); sv[2] = p.x; sv[3] = p.y;
        p = up2(selfw.z); sv[4] = p.x; sv[5] = p.y;
        p = up2(selfw.w); sv[6] = p.x; sv[7] = p.y;
    }
    float t[8];
    if (MODE) {
        float in[8];
        if (act) {
            float deg = (float)(e - sf);
#pragma unroll
            for (int c = 0; c < 8; c++) {
                int f = l * 8 + c;
                in[c] = sv[c] * sSc[f] + sSh[f] + (g[c] * sSc[f] + deg * sSh[f]);
            }
        } else {
#pragma unroll
            for (int c = 0; c < 8; c++) in[c] = 0.f;
        }
#pragma unroll
        for (int c = 0; c < 8; c++) sStage[(l * 8 + c) * SSTR + nl] = in[c];
        __syncthreads();
#pragma unroll
        for (int j = 0; j < 8; j++) t[j] = sBa[l * 8 + j];
        const float4* w4a = reinterpret_cast<const float4*>(sWa);
#pragma unroll
        for (int k = 0; k < 32; k++) {
            float a = sStage[k * SSTR + nl];
            float4 w0 = w4a[k * 8 + 2 * l];
            float4 w1 = w4a[k * 8 + 2 * l + 1];
            t[0] += a * w0.x; t[1] += a * w0.y; t[2] += a * w0.z; t[3] += a * w0.w;
            t[4] += a * w1.x; t[5] += a * w1.y; t[6] += a * w1.z; t[7] += a * w1.w;
        }
#pragma unroll
        for (int j = 0; j < 8; j++) t[j] = fmaxf(t[j], 0.f);
        __syncthreads();   // all GEMM1 reads done before stage reuse
    } else {
        if (act) {
#pragma unroll
            for (int c = 0; c < 8; c++) t[c] = fmaxf(sv[c] + g[c] + sBa[l * 8 + c], 0.f);
        } else {
#pragma unroll
            for (int c = 0; c < 8; c++) t[c] = 0.f;
        }
    }

    // ---- stage t; GEMM2: r = relu(t @ Wb + bb) ----
#pragma unroll
    for (int c = 0; c < 8; c++) sStage[(l * 8 + c) * SSTR + nl] = t[c];
    __syncthreads();
    float r[8];
#pragma unroll
    for (int j = 0; j < 8; j++) r[j] = sBb[l * 8 + j];
    const float4* w4b = reinterpret_cast<const float4*>(sWb);
#pragma unroll
    for (int k = 0; k < 32; k++) {
        float a = sStage[k * SSTR + nl];
        float4 w0 = w4b[k * 8 + 2 * l];
        float4 w1 = w4b[k * 8 + 2 * l + 1];
        r[0] += a * w0.x; r[1] += a * w0.y; r[2] += a * w0.z; r[3] += a * w0.w;
        r[4] += a * w1.x; r[5] += a * w1.y; r[6] += a * w1.z; r[7] += a * w1.w;
    }
#pragma unroll
    for (int j = 0; j < 8; j++) r[j] = fmaxf(r[j], 0.f);

    if (act) {
        uint4 p;
        p.x = pk2(r[0], r[1]); p.y = pk2(r[2], r[3]);
        p.z = pk2(r[4], r[5]); p.w = pk2(r[6], r[7]);
        reinterpret_cast<uint4*>(tblOut)[(long long)node * 4 + l] = p;
    } else {
#pragma unroll
        for (int j = 0; j < 8; j++) r[j] = 0.f;
    }

    // ---- stats: stride-4 wave reduce -> lanes 0..3 hold 8 feats each ----
    int lane = tid & 63, wid = tid >> 6;
#pragma unroll
    for (int j = 0; j < 8; j++) {
        float v = r[j], v2 = v * v;
        v += __shfl_down(v, 32, 64); v2 += __shfl_down(v2, 32, 64);
        v += __shfl_down(v, 16, 64); v2 += __shfl_down(v2, 16, 64);
        v += __shfl_down(v, 8, 64);  v2 += __shfl_down(v2, 8, 64);
        v += __shfl_down(v, 4, 64);  v2 += __shfl_down(v2, 4, 64);
        if (lane < 4) { sSum[wid * 32 + lane * 8 + j] = v; sSq[wid * 32 + lane * 8 + j] = v2; }
    }
    __syncthreads();
    if (tid < 32) {
        float a = sSum[tid] + sSum[32 + tid] + sSum[64 + tid] + sSum[96 + tid];
        float b = sSq[tid] + sSq[32 + tid] + sSq[64 + tid] + sSq[96 + tid];
        atomicAdd(&statsOut[tid], a);
        atomicAdd(&statsOut[32 + tid], b);
    }
}

// ============ pool (fp16 table) with fused BN of layer 5, privatized atomics ============
#define POOL_NPB 512
__global__ __launch_bounds__(256) void pool_bn_k(const unsigned* __restrict__ tbl,
                                                 const int* __restrict__ batch,
                                                 const float* __restrict__ st,
                                                 const float* __restrict__ gamma,
                                                 const float* __restrict__ beta,
                                                 float* __restrict__ pooled) {
    int tid = threadIdx.x;
    int f = tid & 31;
    int p = tid >> 5;
    int wrd = f >> 1;
    int hi = f & 1;
    int n0 = blockIdx.x * POOL_NPB + p * (POOL_NPB / 8);
    int n1 = n0 + POOL_NPB / 8;
    if (n1 > NN) n1 = NN;
    if (n0 >= NN) return;
    const float invn = 1.0f / NN;
    float mu = st[f] * invn;
    float var = st[32 + f] * invn - mu * mu;
    float sc = rsqrtf(var + BN_EPS) * gamma[f];
    float sh = beta[f] - mu * sc;
    float acc = 0.f;
    int cur = batch[n0];
    for (int n = n0; n < n1; n++) {
        int g = batch[n];
        if (g != cur) {
            atomicAdd(&pooled[cur * 32 + f], acc);
            cur = g;
            acc = 0.f;
        }
        float2 pv = up2(tbl[(long long)n * 16 + wrd]);
        acc += (hi ? pv.y : pv.x) * sc + sh;
    }
    atomicAdd(&pooled[cur * 32 + f], acc);
}

// ============ final FCs ============
__global__ __launch_bounds__(64) void final_k(const float* __restrict__ pooled,
                                              const float* __restrict__ w1,
                                              const float* __restrict__ b1,
                                              const float* __restrict__ w2,
                                              const float* __restrict__ b2,
                                              float* __restrict__ out) {
    int g = threadIdx.x;
    if (g >= NG) return;
    float t[32];
#pragma unroll
    for (int j = 0; j < 32; j++) t[j] = b1[j];
    for (int k = 0; k < 32; k++) {
        float a = pooled[g * 32 + k];
#pragma unroll
        for (int j = 0; j < 32; j++) t[j] += a * w1[k * 32 + j];
    }
#pragma unroll
    for (int j = 0; j < 32; j++) t[j] = fmaxf(t[j], 0.f);
    for (int c = 0; c < NC; c++) {
        float o = b2[c];
#pragma unroll
        for (int k = 0; k < 32; k++) o += t[k] * w2[k * NC + c];
        out[g * NC + c] = o;
    }
}

extern "C" void kernel_launch(void* const* d_in, const int* in_sizes, int n_in,
                              void* d_out, int out_size, void* d_ws, size_t ws_size,
                              hipStream_t stream) {
    const float* x = (const float*)d_in[0];
    const int* ei = (const int*)d_in[1];
    const int* batch = (const int*)d_in[2];
    const float* w1a = (const float*)d_in[3];
    const float* b1a = (const float*)d_in[4];
    const float* w1b = (const float*)d_in[5];
    const float* b1b = (const float*)d_in[6];
    const float* Wa = (const float*)d_in[7];
    const float* Ba = (const float*)d_in[8];
    const float* Wb = (const float*)d_in[9];
    const float* Bb = (const float*)d_in[10];
    const float* bn_gamma = (const float*)d_in[11];
    const float* bn_beta = (const float*)d_in[12];
    const float* fc1w = (const float*)d_in[13];
    const float* fc1b = (const float*)d_in[14];
    const float* fc2w = (const float*)d_in[15];
    const float* fc2b = (const float*)d_in[16];
    float* out = (float*)d_out;

    float* ws = (float*)d_ws;
    float* stats_all = ws;                            // 5*64
    float* pooled = stats_all + 5 * 64;               // NG*32
    float* agg = pooled + NG * 32;                    // NN*32 f32 (pass-0 partials)
    unsigned* yhf = (unsigned*)(agg + (size_t)NN * 32); // NN*16 uints (32 fp16/row)
    unsigned* hfA = yhf + (size_t)NN * 16;            // NN*16
    unsigned* hfB = hfA + (size_t)NN * 16;            // NN*16
    unsigned* binned = hfB + (size_t)NN * 16;         // NE
    int* bcnt = (int*)(binned + NE);                  // NBUCK
    int* bbase = bcnt + NBUCK;                        // NBUCK+1
    int* bcur = bbase + NBUCK + 1;                    // NBUCK
    int* rowptr = bcur + NBUCK;                       // NN+1
    int* splitp = rowptr + NN + 1;                    // NN
    int* csr = splitp + NN;                           // NE

    const int nb4 = (NN + 63) / 64;   // 1563 blocks, 4 lanes/node

    // ---- CSR build (bucketed, packed, tile-split) ----
    hipMemsetAsync(bcnt, 0, NBUCK * sizeof(int), stream);
    binA_k<<<NCH, 256, 0, stream>>>(ei, bcnt);
    binB_k<<<1, 512, 0, stream>>>(bcnt, bbase, bcur);
    binC_k<<<NCH, 256, 0, stream>>>(ei, bcur, binned);
    binD_k<<<NBUCK, 256, 0, stream>>>(binned, bbase, rowptr, splitp, csr);

    // ---- layer 1: yhf = fp16(x@W1a) (+zero stats/pooled); tiled gather + fused tail ----
    pre1_k<<<nb4, 256, 0, stream>>>(x, w1a, yhf, stats_all);
    gatherT0_k<<<nb4, 256, 0, stream>>>(yhf, rowptr, splitp, csr, agg);
    fused_k<0><<<nb4, 256, 0, stream>>>(yhf, hfA, rowptr, splitp, csr, agg,
                                        nullptr, b1a, w1b, b1b,
                                        nullptr, nullptr, nullptr, stats_all);

    // ---- layers 2-5: tiled gather + fused gather(BN-prev)+MLP; table ping-pong ----
    unsigned* tin = hfA;
    unsigned* tout = hfB;
    for (int i = 0; i < 4; i++) {
        gatherT0_k<<<nb4, 256, 0, stream>>>(tin, rowptr, splitp, csr, agg);
        fused_k<1><<<nb4, 256, 0, stream>>>(tin, tout, rowptr, splitp, csr, agg,
                                            Wa + i * 1024, Ba + i * 32,
                                            Wb + i * 1024, Bb + i * 32,
                                            stats_all + i * 64, bn_gamma + i * 32,
                                            bn_beta + i * 32, stats_all + (i + 1) * 64);
        unsigned* tmp = tin; tin = tout; tout = tmp;
    }

    // ---- pool (BN5 fused, fp16 table) + FCs ----
    pool_bn_k<<<(NN + POOL_NPB - 1) / POOL_NPB, 256, 0, stream>>>(
        tin, batch, stats_all + 4 * 64, bn_gamma + 4 * 32, bn_beta + 4 * 32, pooled);
    final_k<<<1, 64, 0, stream>>>(pooled, fc1w, fc1b, fc2w, fc2b, out);
}

// Round 15
// 509.844 us; speedup vs baseline: 2.0027x; 1.1310x over previous
//
#include <hip/hip_runtime.h>
#include <hip/hip_fp16.h>

#define NN 100000
#define NE 1600000
#define NF 64
#define DM 32
#define NG 64
#define NC 10
#define BN_EPS 1e-5f

#define BSHIFT 8
#define NBUCK ((NN + 255) >> 8)        // 391 buckets of 256 nodes
#define CHUNK 8192                     // edges per binning block
#define NCH ((NE + CHUNK - 1) / CHUNK) // 196

// ---- fp16 pack/unpack helpers (RNE) ----
__device__ __forceinline__ float2 up2(unsigned u) {
    __half2 h = __builtin_bit_cast(__half2, u);
    return __half22float2(h);
}
__device__ __forceinline__ unsigned pk2(float a, float b) {
    __half2 h = __floats2half2_rn(a, b);
    return __builtin_bit_cast(unsigned, h);
}
__device__ __forceinline__ void acc8(float* a, uint4 w) {
    float2 p;
    p = up2(w.x); a[0] += p.x; a[1] += p.y;
    p = up2(w.y); a[2] += p.x; a[3] += p.y;
    p = up2(w.z); a[4] += p.x; a[5] += p.y;
    p = up2(w.w); a[6] += p.x; a[7] += p.y;
}

// ============ CSR build via bucket counting-sort ============
__global__ __launch_bounds__(256) void binA_k(const int* __restrict__ ei,
                                              int* __restrict__ bcnt) {
    __shared__ int h[NBUCK];
    for (int i = threadIdx.x; i < NBUCK; i += 256) h[i] = 0;
    __syncthreads();
    long long base = (long long)blockIdx.x * CHUNK;
    int n = (int)((NE - base < CHUNK) ? (NE - base) : CHUNK);
    for (int i = threadIdx.x; i < n; i += 256) {
        int d = ei[NE + base + i];
        atomicAdd(&h[d >> BSHIFT], 1);
    }
    __syncthreads();
    for (int i = threadIdx.x; i < NBUCK; i += 256)
        if (h[i]) atomicAdd(&bcnt[i], h[i]);
}

__global__ __launch_bounds__(512) void binB_k(const int* __restrict__ bcnt,
                                              int* __restrict__ bbase,
                                              int* __restrict__ bcur) {
    __shared__ int s[512];
    int t = threadIdx.x;
    int v = (t < NBUCK) ? bcnt[t] : 0;
    s[t] = v;
    __syncthreads();
    int acc = v;
    for (int off = 1; off < 512; off <<= 1) {
        int add = (t >= off) ? s[t - off] : 0;
        __syncthreads();
        acc += add;
        s[t] = acc;
        __syncthreads();
    }
    if (t < NBUCK) { bbase[t] = acc - v; bcur[t] = acc - v; }
    if (t == 0) bbase[NBUCK] = NE;
}

__global__ __launch_bounds__(256) void binC_k(const int* __restrict__ ei,
                                              int* __restrict__ bcur,
                                              unsigned* __restrict__ binned) {
    __shared__ int cnt[NBUCK];
    __shared__ int ofs[NBUCK];
    __shared__ int idx[NBUCK];
    for (int i = threadIdx.x; i < NBUCK; i += 256) { cnt[i] = 0; idx[i] = 0; }
    __syncthreads();
    long long base = (long long)blockIdx.x * CHUNK;
    int n = (int)((NE - base < CHUNK) ? (NE - base) : CHUNK);
    int d[CHUNK / 256];
#pragma unroll
    for (int k = 0; k < CHUNK / 256; k++) {
        int i = threadIdx.x + k * 256;
        int dd = (i < n) ? ei[NE + base + i] : -1;
        d[k] = dd;
        if (dd >= 0) atomicAdd(&cnt[dd >> BSHIFT], 1);
    }
    __syncthreads();
    for (int i = threadIdx.x; i < NBUCK; i += 256)
        if (cnt[i]) ofs[i] = atomicAdd(&bcur[i], cnt[i]);
    __syncthreads();
#pragma unroll
    for (int k = 0; k < CHUNK / 256; k++) {
        int i = threadIdx.x + k * 256;
        if (i < n) {
            unsigned src = (unsigned)ei[base + i];
            int b = d[k] >> BSHIFT;
            int l = atomicAdd(&idx[b], 1);
            binned[ofs[b] + l] = (src << 8) | (unsigned)(d[k] & 255);
        }
    }
}

__global__ __launch_bounds__(256) void binD_k(const unsigned* __restrict__ binned,
                                              const int* __restrict__ bbase,
                                              int* __restrict__ rowptr,
                                              int* __restrict__ csr) {
    __shared__ int cnt[256];
    __shared__ int cur[256];
    __shared__ int s[256];
    int b = blockIdx.x;
    int e0 = bbase[b], e1 = bbase[b + 1];
    int t = threadIdx.x;
    cnt[t] = 0;
    __syncthreads();
    for (int e = e0 + t; e < e1; e += 256) atomicAdd(&cnt[binned[e] & 255u], 1);
    __syncthreads();
    int v = cnt[t];
    s[t] = v;
    __syncthreads();
    int acc = v;
    for (int off = 1; off < 256; off <<= 1) {
        int add = (t >= off) ? s[t - off] : 0;
        __syncthreads();
        acc += add;
        s[t] = acc;
        __syncthreads();
    }
    int base = e0 + acc - v;
    int node = (b << BSHIFT) + t;
    if (node < NN) rowptr[node] = base;
    cur[t] = base;
    if (b == NBUCK - 1 && t == 0) rowptr[NN] = NE;
    __syncthreads();
    for (int e = e0 + t; e < e1; e += 256) {
        unsigned w = binned[e];
        int p = atomicAdd(&cur[w & 255u], 1);
        csr[p] = (int)(w >> 8);
    }
}

// ============ pre-pass layer 1: yhf = fp16(x @ W1a), 4 lanes/node; zero accumulators ============
__global__ __launch_bounds__(256) void pre1_k(const float* __restrict__ x,
                                              const float* __restrict__ wa,
                                              unsigned* __restrict__ yhf,
                                              float* __restrict__ zbuf) {
    __shared__ float sWa[64 * 32];
    int tid = threadIdx.x;
    if (blockIdx.x == 0) {
        for (int i = tid; i < 5 * 64 + NG * 32; i += 256) zbuf[i] = 0.f;
    }
    for (int i = tid; i < 64 * 32; i += 256) sWa[i] = wa[i];
    __syncthreads();
    int l = tid & 3;
    int node = blockIdx.x * 64 + (tid >> 2);
    if (node >= NN) return;
    float t[8];
#pragma unroll
    for (int j = 0; j < 8; j++) t[j] = 0.f;
    const float4* xr = reinterpret_cast<const float4*>(x + (long long)node * 64);
    const float4* w4 = reinterpret_cast<const float4*>(sWa);
#pragma unroll
    for (int k4 = 0; k4 < 16; k4++) {
        float4 xv = xr[k4];
        float av[4] = {xv.x, xv.y, xv.z, xv.w};
#pragma unroll
        for (int i = 0; i < 4; i++) {
            float a = av[i];
            float4 w0 = w4[(k4 * 4 + i) * 8 + 2 * l];
            float4 w1 = w4[(k4 * 4 + i) * 8 + 2 * l + 1];
            t[0] += a * w0.x; t[1] += a * w0.y; t[2] += a * w0.z; t[3] += a * w0.w;
            t[4] += a * w1.x; t[5] += a * w1.y; t[6] += a * w1.z; t[7] += a * w1.w;
        }
    }
    uint4 p;
    p.x = pk2(t[0], t[1]); p.y = pk2(t[2], t[3]);
    p.z = pk2(t[4], t[5]); p.w = pk2(t[6], t[7]);
    reinterpret_cast<uint4*>(yhf)[(long long)node * 4 + l] = p;
}

// ============ fused gather + MLP + BN-stats, 4 lanes/node, 64 nodes/block ============
// All inter-layer state lives in fp16 tables; self row read from tblIn.
// Gather unroll x4 (R9-proven sweet spot; x8 costs ~5us/layer in regs/waitcnt).
// MODE 0: t = relu(self + gathersum + ba); r = relu(t@Wb + bb)
// MODE 1: in = BN(self) + (sc*gathersum + deg*sh); t = relu(in@Wa + ba); r = relu(t@Wb + bb)
#define SSTR 65
template <int MODE>
__global__ __launch_bounds__(256) void fused_k(const unsigned* __restrict__ tblIn,
                                               unsigned* __restrict__ tblOut,
                                               const int* __restrict__ rowptr,
                                               const int* __restrict__ csr,
                                               const float* __restrict__ wa,
                                               const float* __restrict__ ba,
                                               const float* __restrict__ wb,
                                               const float* __restrict__ bb,
                                               const float* __restrict__ stPrev,
                                               const float* __restrict__ gammaPrev,
                                               const float* __restrict__ betaPrev,
                                               float* __restrict__ statsOut) {
    __shared__ float sWa[32 * 32];
    __shared__ float sWb[32 * 32];
    __shared__ float sBa[32], sBb[32];
    __shared__ float sSc[32], sSh[32];
    __shared__ float sStage[32 * SSTR];
    __shared__ float sSum[4 * 32], sSq[4 * 32];
    int tid = threadIdx.x;
    for (int i = tid; i < 32 * 32; i += 256) {
        sWb[i] = wb[i];
        if (MODE) sWa[i] = wa[i];
    }
    if (tid < 32) {
        sBa[tid] = ba[tid];
        sBb[tid] = bb[tid];
        if (MODE) {
            const float invn = 1.0f / NN;
            float mu = stPrev[tid] * invn;
            float var = stPrev[32 + tid] * invn - mu * mu;
            float scale = rsqrtf(var + BN_EPS) * gammaPrev[tid];
            sSc[tid] = scale;
            sSh[tid] = betaPrev[tid] - mu * scale;
        }
    }

    int l = tid & 3;
    int nl = tid >> 2;
    int node = blockIdx.x * 64 + nl;
    bool act = node < NN;

    // ---- gather phase (fp16 table, fp32 accum), self row prefetched, unroll x4 ----
    int s = 0, e = 0;
    uint4 selfw = make_uint4(0, 0, 0, 0);
    const uint4* t4 = reinterpret_cast<const uint4*>(tblIn);
    if (act) {
        s = rowptr[node];
        e = rowptr[node + 1];
        selfw = t4[(long long)node * 4 + l];
    }
    float g[8];
#pragma unroll
    for (int c = 0; c < 8; c++) g[c] = 0.f;
    int i = s;
    for (; i + 4 <= e; i += 4) {
        int s0 = csr[i], s1 = csr[i + 1], s2 = csr[i + 2], s3 = csr[i + 3];
        uint4 w0 = t4[(long long)s0 * 4 + l];
        uint4 w1 = t4[(long long)s1 * 4 + l];
        uint4 w2 = t4[(long long)s2 * 4 + l];
        uint4 w3 = t4[(long long)s3 * 4 + l];
        acc8(g, w0); acc8(g, w1); acc8(g, w2); acc8(g, w3);
    }
    for (; i < e; i++) {
        uint4 w = t4[(long long)csr[i] * 4 + l];
        acc8(g, w);
    }
    __syncthreads();   // weights, biases, BN consts ready; gather done

    // ---- self-row + (BN) combine; stage GEMM input / t ----
    float sv[8];
    {
        float2 p;
        p = up2(selfw.x); sv[0] = p.x; sv[1] = p.y;
        p = up2(selfw.y); sv[2] = p.x; sv[3] = p.y;
        p = up2(selfw.z); sv[4] = p.x; sv[5] = p.y;
        p = up2(selfw.w); sv[6] = p.x; sv[7] = p.y;
    }
    float t[8];
    if (MODE) {
        float in[8];
        if (act) {
            float deg = (float)(e - s);
#pragma unroll
            for (int c = 0; c < 8; c++) {
                int f = l * 8 + c;
                in[c] = sv[c] * sSc[f] + sSh[f] + (g[c] * sSc[f] + deg * sSh[f]);
            }
        } else {
#pragma unroll
            for (int c = 0; c < 8; c++) in[c] = 0.f;
        }
#pragma unroll
        for (int c = 0; c < 8; c++) sStage[(l * 8 + c) * SSTR + nl] = in[c];
        __syncthreads();
#pragma unroll
        for (int j = 0; j < 8; j++) t[j] = sBa[l * 8 + j];
        const float4* w4a = reinterpret_cast<const float4*>(sWa);
#pragma unroll
        for (int k = 0; k < 32; k++) {
            float a = sStage[k * SSTR + nl];
            float4 w0 = w4a[k * 8 + 2 * l];
            float4 w1 = w4a[k * 8 + 2 * l + 1];
            t[0] += a * w0.x; t[1] += a * w0.y; t[2] += a * w0.z; t[3] += a * w0.w;
            t[4] += a * w1.x; t[5] += a * w1.y; t[6] += a * w1.z; t[7] += a * w1.w;
        }
#pragma unroll
        for (int j = 0; j < 8; j++) t[j] = fmaxf(t[j], 0.f);
        __syncthreads();   // all GEMM1 reads done before stage reuse
    } else {
        if (act) {
#pragma unroll
            for (int c = 0; c < 8; c++) t[c] = fmaxf(sv[c] + g[c] + sBa[l * 8 + c], 0.f);
        } else {
#pragma unroll
            for (int c = 0; c < 8; c++) t[c] = 0.f;
        }
    }

    // ---- stage t; GEMM2: r = relu(t @ Wb + bb) ----
#pragma unroll
    for (int c = 0; c < 8; c++) sStage[(l * 8 + c) * SSTR + nl] = t[c];
    __syncthreads();
    float r[8];
#pragma unroll
    for (int j = 0; j < 8; j++) r[j] = sBb[l * 8 + j];
    const float4* w4b = reinterpret_cast<const float4*>(sWb);
#pragma unroll
    for (int k = 0; k < 32; k++) {
        float a = sStage[k * SSTR + nl];
        float4 w0 = w4b[k * 8 + 2 * l];
        float4 w1 = w4b[k * 8 + 2 * l + 1];
        r[0] += a * w0.x; r[1] += a * w0.y; r[2] += a * w0.z; r[3] += a * w0.w;
        r[4] += a * w1.x; r[5] += a * w1.y; r[6] += a * w1.z; r[7] += a * w1.w;
    }
#pragma unroll
    for (int j = 0; j < 8; j++) r[j] = fmaxf(r[j], 0.f);

    if (act) {
        uint4 p;
        p.x = pk2(r[0], r[1]); p.y = pk2(r[2], r[3]);
        p.z = pk2(r[4], r[5]); p.w = pk2(r[6], r[7]);
        reinterpret_cast<uint4*>(tblOut)[(long long)node * 4 + l] = p;
    } else {
#pragma unroll
        for (int j = 0; j < 8; j++) r[j] = 0.f;
    }

    // ---- stats: stride-4 wave reduce -> lanes 0..3 hold 8 feats each ----
    int lane = tid & 63, wid = tid >> 6;
#pragma unroll
    for (int j = 0; j < 8; j++) {
        float v = r[j], v2 = v * v;
        v += __shfl_down(v, 32, 64); v2 += __shfl_down(v2, 32, 64);
        v += __shfl_down(v, 16, 64); v2 += __shfl_down(v2, 16, 64);
        v += __shfl_down(v, 8, 64);  v2 += __shfl_down(v2, 8, 64);
        v += __shfl_down(v, 4, 64);  v2 += __shfl_down(v2, 4, 64);
        if (lane < 4) { sSum[wid * 32 + lane * 8 + j] = v; sSq[wid * 32 + lane * 8 + j] = v2; }
    }
    __syncthreads();
    if (tid < 32) {
        float a = sSum[tid] + sSum[32 + tid] + sSum[64 + tid] + sSum[96 + tid];
        float b = sSq[tid] + sSq[32 + tid] + sSq[64 + tid] + sSq[96 + tid];
        atomicAdd(&statsOut[tid], a);
        atomicAdd(&statsOut[32 + tid], b);
    }
}

// ============ pool (fp16 table) with fused BN of layer 5, privatized atomics ============
#define POOL_NPB 512
__global__ __launch_bounds__(256) void pool_bn_k(const unsigned* __restrict__ tbl,
                                                 const int* __restrict__ batch,
                                                 const float* __restrict__ st,
                                                 const float* __restrict__ gamma,
                                                 const float* __restrict__ beta,
                                                 float* __restrict__ pooled) {
    int tid = threadIdx.x;
    int f = tid & 31;
    int p = tid >> 5;
    int wrd = f >> 1;
    int hi = f & 1;
    int n0 = blockIdx.x * POOL_NPB + p * (POOL_NPB / 8);
    int n1 = n0 + POOL_NPB / 8;
    if (n1 > NN) n1 = NN;
    if (n0 >= NN) return;
    const float invn = 1.0f / NN;
    float mu = st[f] * invn;
    float var = st[32 + f] * invn - mu * mu;
    float sc = rsqrtf(var + BN_EPS) * gamma[f];
    float sh = beta[f] - mu * sc;
    float acc = 0.f;
    int cur = batch[n0];
    for (int n = n0; n < n1; n++) {
        int g = batch[n];
        if (g != cur) {
            atomicAdd(&pooled[cur * 32 + f], acc);
            cur = g;
            acc = 0.f;
        }
        float2 pv = up2(tbl[(long long)n * 16 + wrd]);
        acc += (hi ? pv.y : pv.x) * sc + sh;
    }
    atomicAdd(&pooled[cur * 32 + f], acc);
}

// ============ final FCs ============
__global__ __launch_bounds__(64) void final_k(const float* __restrict__ pooled,
                                              const float* __restrict__ w1,
                                              const float* __restrict__ b1,
                                              const float* __restrict__ w2,
                                              const float* __restrict__ b2,
                                              float* __restrict__ out) {
    int g = threadIdx.x;
    if (g >= NG) return;
    float t[32];
#pragma unroll
    for (int j = 0; j < 32; j++) t[j] = b1[j];
    for (int k = 0; k < 32; k++) {
        float a = pooled[g * 32 + k];
#pragma unroll
        for (int j = 0; j < 32; j++) t[j] += a * w1[k * 32 + j];
    }
#pragma unroll
    for (int j = 0; j < 32; j++) t[j] = fmaxf(t[j], 0.f);
    for (int c = 0; c < NC; c++) {
        float o = b2[c];
#pragma unroll
        for (int k = 0; k < 32; k++) o += t[k] * w2[k * NC + c];
        out[g * NC + c] = o;
    }
}

extern "C" void kernel_launch(void* const* d_in, const int* in_sizes, int n_in,
                              void* d_out, int out_size, void* d_ws, size_t ws_size,
                              hipStream_t stream) {
    const float* x = (const float*)d_in[0];
    const int* ei = (const int*)d_in[1];
    const int* batch = (const int*)d_in[2];
    const float* w1a = (const float*)d_in[3];
    const float* b1a = (const float*)d_in[4];
    const float* w1b = (const float*)d_in[5];
    const float* b1b = (const float*)d_in[6];
    const float* Wa = (const float*)d_in[7];
    const float* Ba = (const float*)d_in[8];
    const float* Wb = (const float*)d_in[9];
    const float* Bb = (const float*)d_in[10];
    const float* bn_gamma = (const float*)d_in[11];
    const float* bn_beta = (const float*)d_in[12];
    const float* fc1w = (const float*)d_in[13];
    const float* fc1b = (const float*)d_in[14];
    const float* fc2w = (const float*)d_in[15];
    const float* fc2b = (const float*)d_in[16];
    float* out = (float*)d_out;

    float* ws = (float*)d_ws;
    float* stats_all = ws;                            // 5*64
    float* pooled = stats_all + 5 * 64;               // NG*32
    unsigned* yhf = (unsigned*)(pooled + NG * 32);    // NN*16 uints (32 fp16/row)
    unsigned* hfA = yhf + (size_t)NN * 16;            // NN*16
    unsigned* hfB = hfA + (size_t)NN * 16;            // NN*16
    unsigned* binned = hfB + (size_t)NN * 16;         // NE
    int* bcnt = (int*)(binned + NE);                  // NBUCK
    int* bbase = bcnt + NBUCK;                        // NBUCK+1
    int* bcur = bbase + NBUCK + 1;                    // NBUCK
    int* rowptr = bcur + NBUCK;                       // NN+1
    int* csr = rowptr + NN + 1;                       // NE

    const int nb4 = (NN + 63) / 64;   // 1563 blocks, 4 lanes/node

    // ---- CSR build (bucketed, packed) ----
    hipMemsetAsync(bcnt, 0, NBUCK * sizeof(int), stream);
    binA_k<<<NCH, 256, 0, stream>>>(ei, bcnt);
    binB_k<<<1, 512, 0, stream>>>(bcnt, bbase, bcur);
    binC_k<<<NCH, 256, 0, stream>>>(ei, bcur, binned);
    binD_k<<<NBUCK, 256, 0, stream>>>(binned, bbase, rowptr, csr);

    // ---- layer 1: yhf = fp16(x@W1a) (+zero stats/pooled); fused gather+tail ----
    pre1_k<<<nb4, 256, 0, stream>>>(x, w1a, yhf, stats_all);
    fused_k<0><<<nb4, 256, 0, stream>>>(yhf, hfA, rowptr, csr,
                                        nullptr, b1a, w1b, b1b,
                                        nullptr, nullptr, nullptr, stats_all);

    // ---- layers 2-5: fused gather(BN-prev) + MLP; fp16 table ping-pong ----
    unsigned* tin = hfA;
    unsigned* tout = hfB;
    for (int i = 0; i < 4; i++) {
        fused_k<1><<<nb4, 256, 0, stream>>>(tin, tout, rowptr, csr,
                                            Wa + i * 1024, Ba + i * 32,
                                            Wb + i * 1024, Bb + i * 32,
                                            stats_all + i * 64, bn_gamma + i * 32,
                                            bn_beta + i * 32, stats_all + (i + 1) * 64);
        unsigned* tmp = tin; tin = tout; tout = tmp;
    }

    // ---- pool (BN5 fused, fp16 table) + FCs ----
    pool_bn_k<<<(NN + POOL_NPB - 1) / POOL_NPB, 256, 0, stream>>>(
        tin, batch, stats_all + 4 * 64, bn_gamma + 4 * 32, bn_beta + 4 * 32, pooled);
    final_k<<<1, 64, 0, stream>>>(pooled, fc1w, fc1b, fc2w, fc2b, out);
}